// Round 1
// 916.314 us; speedup vs baseline: 2.2311x; 2.2311x over previous
//
#include <hip/hip_runtime.h>
#include <math.h>

#ifndef M_PI
#define M_PI 3.14159265358979323846
#endif

#define NN   64
#define CC   256
#define SS   30
#define HWW  176
#define TOPK 10
#define PP   (SS * HWW)          // 5280 positions per (n, c)

typedef __attribute__((ext_vector_type(8))) short short8;   // 8 bf16 = 4 VGPR (MFMA A/B frag)
typedef __attribute__((ext_vector_type(4))) float f32x4;    // MFMA C/D frag
typedef __attribute__((ext_vector_type(4))) int   i32x4;    // 16B staging granule

// RNE f32 -> bf16 (data is finite: no NaN guard needed)
__device__ __forceinline__ unsigned short bf16_rne(float x) {
    unsigned u = __float_as_uint(x);
    u += 0x7FFFu + ((u >> 16) & 1u);
    return (unsigned short)(u >> 16);
}
__device__ __forceinline__ float bf16f(unsigned short s) {
    return __uint_as_float(((unsigned)s) << 16);
}

// ---------------------------------------------------------------------------
// K0: exact spatial filter h[d] in fp64 (Chebyshev cos recurrence), plus
//   (a) hh[0..511]: doubled fp32 table (fallback kernel), and
//   (b) Hsp[3][256][256] bf16: triple-split circulant matrix
//       Hsp[s][c][k] = split_s(h[(c-k) & 255]), splits taken from the fp64 h
//       so h0+h1+h2 carries ~27 mantissa bits.
//   NOTE: h's tail only decays to ~1e-6 (Nyquist kink) -> NO truncation
//   admissible (R2/R3 post-mortem) — full K=256 retained.
// ---------------------------------------------------------------------------
__global__ void build_filter_kernel(float* __restrict__ hh,
                                    unsigned short* __restrict__ Hsp,
                                    int do_hsp) {
    __shared__ unsigned short sh0[256], sh1[256], sh2[256];
    const int d = threadIdx.x;           // 0..255
    const double theta = (2.0 * M_PI * (double)d) / 256.0;
    const double ct = cos(theta);
    double cm_prev = 1.0;
    double cm = ct;
    double acc = 0.0;
    for (int m = 1; m <= 127; ++m) {
        const double mm = (double)m / 32.0;
        const double G = exp(-0.5 * mm * mm);
        acc += G * cm;
        const double cn = 2.0 * ct * cm - cm_prev;
        cm_prev = cm;
        cm = cn;
    }
    const double G128 = exp(-8.0);
    double h = 1.0 + 2.0 * acc + ((d & 1) ? -G128 : G128);
    h /= 256.0;
    hh[d]       = (float)h;
    hh[d + 256] = (float)h;

    if (do_hsp) {
        const unsigned short s0 = bf16_rne((float)h);
        double r = h - (double)bf16f(s0);
        const unsigned short s1 = bf16_rne((float)r);
        r -= (double)bf16f(s1);
        const unsigned short s2 = bf16_rne((float)r);
        sh0[d] = s0; sh1[d] = s1; sh2[d] = s2;
        __syncthreads();
        // coalesced fill: e enumerates (c,k), k fastest
        for (int e = d; e < 65536; e += 256) {
            const int c  = e >> 8;
            const int k  = e & 255;
            const int dd = (c - k) & 255;
            Hsp[e]          = sh0[dd];
            Hsp[65536 + e]  = sh1[dd];
            Hsp[131072 + e] = sh2[dd];
        }
    }
}

// ---------------------------------------------------------------------------
// K1 (rewritten): circulant conv as MFMA GEMM  LOW = H(256x256) @ X(256x5280)
// per n, fp32 emulated via bf16 triple-split, 6 products:
//   aH += H0*X0                                  (dominant, own accumulator)
//   aL += H0*X1 + H1*X0 + H0*X2 + H1*X1 + H2*X0  (~2^-9 corrections)
// low = aH + aL; dropped terms ~2^-26/tap.  Epilogue computes
// score = |low| / (|low - x| + 1e-6) with exact fp32 x from global.
//
// Tiling: block 256 thr (4 waves, 2Mx2N), tile 64(c) x 64(p) x K-chunks of 64.
// LDS 48KB total -> 3 blocks/CU.  Both LDS tiles are [split][row][64 bf16]
// (128B rows) with XOR swizzle  byte ^= (row&7)<<4  -> ds_read_b128 frags are
// conflict-free per 16-lane quarter (m136: 2-way is free).
// MFMA facts used (HW-measured): A row = lane&15 / B col = lane&15 with 8
// k-contiguous elems per lane; C/D col = lane&15, row = (lane>>4)*4 + reg.
// k-slot order inside a frag cancels because A and B use the same convention.
// ---------------------------------------------------------------------------
__global__ __launch_bounds__(256)
void conv_mfma_kernel(const float* __restrict__ seqs,
                      const unsigned short* __restrict__ Hsp,
                      float* __restrict__ scores,
                      int n0)
{
    __shared__ unsigned short As[3][64][64];   // 24KB: [split][c_local][k_local] (swizzled rows)
    __shared__ unsigned short Bs[3][64][64];   // 24KB: [split][p_local][k_local] (swizzled rows)

    const int tid  = threadIdx.x;
    const int lane = tid & 63;
    const int wid  = tid >> 6;          // 0..3
    const int wm   = wid >> 1;          // wave M index (0..1) -> c offset 32*wm
    const int wn   = wid & 1;           // wave N index (0..1) -> p offset 32*wn
    const int ptile = blockIdx.x;       // 0..82   (83*64 >= 5280)
    const int ctile = blockIdx.y;       // 0..3
    const int nrel  = blockIdx.z;
    const int n     = n0 + nrel;
    const int p0 = ptile * 64;
    const int c0 = ctile * 64;
    const size_t nbase = (size_t)n * CC * PP;

    const int l15 = lane & 15;
    const int lq  = lane >> 4;

    f32x4 aH[2][2], aL[2][2];
    #pragma unroll
    for (int a = 0; a < 2; ++a) {
        #pragma unroll
        for (int b = 0; b < 2; ++b) {
            aH[a][b] = (f32x4){0.f, 0.f, 0.f, 0.f};
            aL[a][b] = (f32x4){0.f, 0.f, 0.f, 0.f};
        }
    }

    // B-staging thread mapping: k-pair = tid>>3, p = 8*j + (tid&7) (strided p
    // keeps ds_write banks spread; global reads still coalesce in 32B runs).
    const int skp = tid >> 3;           // 0..31 -> k_local {2skp, 2skp+1}
    const int sr  = tid & 7;

    for (int kc = 0; kc < 4; ++kc) {
        const int k0 = kc * 64;
        if (kc) __syncthreads();        // previous compute done before overwrite

        // ---- stage A: 1536 16B granules of Hsp (L2/L3-hot, 384KB shared by all blocks)
        #pragma unroll
        for (int i = 0; i < 6; ++i) {
            const int idx = i * 256 + tid;       // 0..1535 = [sg][cc][g]
            const int sg  = idx >> 9;
            const int cc  = (idx >> 3) & 63;
            const int g   = idx & 7;
            const i32x4 v = *(const i32x4*)(Hsp + ((size_t)(sg * 256 + c0 + cc) << 8)
                                                + (k0 + 8 * g));
            *(i32x4*)((char*)(&As[sg][cc][0]) + ((16 * g) ^ ((cc & 7) << 4))) = v;
        }

        // ---- stage B: load fp32 X rows, triple-split, transposed write [p][k]
        {
            const int ka = k0 + 2 * skp;
            const float* __restrict__ rowA = seqs + nbase + (size_t)ka * PP + p0;
            const float* __restrict__ rowB = rowA + PP;
            float xa[8], xb[8];
            #pragma unroll
            for (int j = 0; j < 8; ++j) {
                const int pl  = 8 * j + sr;
                const int plc = (p0 + pl < PP) ? pl : (PP - 1 - p0);  // tail clamp (stores guarded)
                xa[j] = rowA[plc];
                xb[j] = rowB[plc];
            }
            #pragma unroll
            for (int j = 0; j < 8; ++j) {
                const int pl = 8 * j + sr;
                const unsigned short a0 = bf16_rne(xa[j]);
                const float ra          = xa[j] - bf16f(a0);
                const unsigned short a1 = bf16_rne(ra);
                const unsigned short a2 = bf16_rne(ra - bf16f(a1));
                const unsigned short b0 = bf16_rne(xb[j]);
                const float rb          = xb[j] - bf16f(b0);
                const unsigned short b1 = bf16_rne(rb);
                const unsigned short b2 = bf16_rne(rb - bf16f(b1));
                char* wp = (char*)(&Bs[0][pl][0]) + ((4 * skp) ^ ((pl & 7) << 4));
                *(unsigned int*)(wp)         = (unsigned)a0 | ((unsigned)b0 << 16);
                *(unsigned int*)(wp + 8192)  = (unsigned)a1 | ((unsigned)b1 << 16);
                *(unsigned int*)(wp + 16384) = (unsigned)a2 | ((unsigned)b2 << 16);
            }
        }
        __syncthreads();

        // ---- compute: 2 kfrags (K=32 each) x 4 frag-pairs x 6 products
        #pragma unroll
        for (int kf = 0; kf < 2; ++kf) {
            short8 Af[2][3], Bf[2][3];
            #pragma unroll
            for (int mf = 0; mf < 2; ++mf) {
                const int c = wm * 32 + mf * 16 + l15;
                const char* bp = (const char*)(&As[0][c][0])
                               + ((64 * kf + 16 * lq) ^ ((c & 7) << 4));
                Af[mf][0] = *(const short8*)(bp);
                Af[mf][1] = *(const short8*)(bp + 8192);
                Af[mf][2] = *(const short8*)(bp + 16384);
            }
            #pragma unroll
            for (int nf = 0; nf < 2; ++nf) {
                const int p = wn * 32 + nf * 16 + l15;
                const char* bp = (const char*)(&Bs[0][p][0])
                               + ((64 * kf + 16 * lq) ^ ((p & 7) << 4));
                Bf[nf][0] = *(const short8*)(bp);
                Bf[nf][1] = *(const short8*)(bp + 8192);
                Bf[nf][2] = *(const short8*)(bp + 16384);
            }
            #pragma unroll
            for (int mf = 0; mf < 2; ++mf) {
                #pragma unroll
                for (int nf = 0; nf < 2; ++nf) {
                    aH[mf][nf] = __builtin_amdgcn_mfma_f32_16x16x32_bf16(Af[mf][0], Bf[nf][0], aH[mf][nf], 0, 0, 0);
                    aL[mf][nf] = __builtin_amdgcn_mfma_f32_16x16x32_bf16(Af[mf][0], Bf[nf][1], aL[mf][nf], 0, 0, 0);
                    aL[mf][nf] = __builtin_amdgcn_mfma_f32_16x16x32_bf16(Af[mf][1], Bf[nf][0], aL[mf][nf], 0, 0, 0);
                    aL[mf][nf] = __builtin_amdgcn_mfma_f32_16x16x32_bf16(Af[mf][0], Bf[nf][2], aL[mf][nf], 0, 0, 0);
                    aL[mf][nf] = __builtin_amdgcn_mfma_f32_16x16x32_bf16(Af[mf][1], Bf[nf][1], aL[mf][nf], 0, 0, 0);
                    aL[mf][nf] = __builtin_amdgcn_mfma_f32_16x16x32_bf16(Af[mf][2], Bf[nf][0], aL[mf][nf], 0, 0, 0);
                }
            }
        }
    }

    // ---- epilogue: low = aH + aL, score from exact fp32 center value
    #pragma unroll
    for (int mf = 0; mf < 2; ++mf) {
        #pragma unroll
        for (int nf = 0; nf < 2; ++nf) {
            const int pg = p0 + wn * 32 + nf * 16 + l15;
            if (pg < PP) {
                #pragma unroll
                for (int rg = 0; rg < 4; ++rg) {
                    const int c = c0 + wm * 32 + mf * 16 + lq * 4 + rg;
                    const float low = aH[mf][nf][rg] + aL[mf][nf][rg];
                    const float x = seqs[nbase + (size_t)c * PP + pg];
                    scores[((size_t)nrel * CC + c) * PP + pg] =
                        fabsf(low) / (fabsf(low - x) + 1e-6f);
                }
            }
        }
    }
}

// ---------------------------------------------------------------------------
// K2: per-(n,c,hw) thread.  30 score + 30 x coalesced loads; bitmask top-10
// (strict >, ascending s => lowest-index tie-break = lax.top_k), selected x
// tracked through the same cndmask chain; fused max-pool + sigmoid blend.
// (unchanged this round — next target: ~390us vs ~150us floor)
// ---------------------------------------------------------------------------
__device__ __forceinline__ float tmax30(const float* v) {
    float m[15];
    #pragma unroll
    for (int i = 0; i < 15; ++i) m[i] = fmaxf(v[i], v[i + 15]);
    #pragma unroll
    for (int i = 0; i < 7; ++i) m[i] = fmaxf(m[i], m[i + 8]);
    #pragma unroll
    for (int i = 0; i < 4; ++i) m[i] = fmaxf(m[i], m[i + 4]);
    m[0] = fmaxf(m[0], m[2]);
    m[1] = fmaxf(m[1], m[3]);
    return fmaxf(m[0], m[1]);
}

__global__ __launch_bounds__(256)
void topk_pool_kernel(const float* __restrict__ seqs,
                      const float* __restrict__ scores,
                      const float* __restrict__ logit_p,
                      float* __restrict__ out,
                      int n0) {
    const int tid  = threadIdx.x;
    const int lane = tid & 63;
    const int cq   = tid >> 6;                 // 0..3
    const int hwt  = blockIdx.x;               // 0..2
    const int cg   = blockIdx.y;               // 0..63
    const int nrel = blockIdx.z;
    const int n    = n0 + nrel;
    const int c    = cg * 4 + cq;
    const int hw   = hwt * 64 + lane;
    const bool valid = (hw < HWW);
    const int hwc  = valid ? hw : HWW - 1;

    const size_t bx = ((size_t)(n    * CC + c) * SS) * HWW + hwc;
    const size_t bk = ((size_t)(nrel * CC + c) * SS) * HWW + hwc;

    float xk[SS], kk[SS];
    #pragma unroll
    for (int s = 0; s < SS; ++s) xk[s] = seqs[bx + (size_t)s * HWW];
    #pragma unroll
    for (int s = 0; s < SS; ++s) kk[s] = scores[bk + (size_t)s * HWW];

    const float mx = tmax30(xk);

    unsigned taken = 0u;
    float sum = 0.0f;
    #pragma unroll 1
    for (int p = 0; p < TOPK; ++p) {
        float best = -1.0f;                    // scores >= 0
        float bxv  = 0.0f;
        unsigned bbit = 0u;
        #pragma unroll
        for (int s = 0; s < SS; ++s) {
            const bool ok = (((taken >> s) & 1u) == 0u) && (kk[s] > best);
            best = ok ? kk[s] : best;
            bxv  = ok ? xk[s] : bxv;
            bbit = ok ? (1u << s) : bbit;
        }
        taken |= bbit;
        sum += bxv;
    }

    const float alpha = 1.0f / (1.0f + expf(-logit_p[0]));
    if (valid)
        out[((size_t)n * CC + c) * HWW + hw] =
            alpha * (sum * 0.1f) + (1.0f - alpha) * mx;
}

// ---------------------------------------------------------------------------
// Fallback (round-1 kernel, known-correct): only if ws is too small.
// ---------------------------------------------------------------------------
__global__ __launch_bounds__(64, 3)
void fallback_pool_kernel(const float* __restrict__ seqs,
                          const float* __restrict__ logit_p,
                          const float* __restrict__ hh_g,
                          float* __restrict__ out) {
    __shared__ float hh[512];
    const int lane = threadIdx.x;
    const int hw = blockIdx.x % HWW;
    const int n  = blockIdx.x / HWW;
    for (int i = lane; i < 512; i += 64) hh[i] = hh_g[i];
    __syncthreads();

    float acc[4][SS];
    #pragma unroll
    for (int j = 0; j < 4; ++j)
        #pragma unroll
        for (int s = 0; s < SS; ++s) acc[j][s] = 0.0f;

    const size_t row_stride = (size_t)SS * HWW;
    const float* __restrict__ xbase = seqs + (size_t)n * CC * row_stride + hw;

    for (int k = 0; k < CC; ++k) {
        const float* __restrict__ xrow = xbase + (size_t)k * row_stride;
        const int hbase = lane + 256 - k;
        const float h0 = hh[hbase];
        const float h1 = hh[hbase + 64];
        const float h2 = hh[hbase + 128];
        const float h3 = hh[hbase + 192];
        #pragma unroll
        for (int s = 0; s < SS; ++s) {
            const float xv = xrow[(size_t)s * HWW];
            acc[0][s] = fmaf(xv, h0, acc[0][s]);
            acc[1][s] = fmaf(xv, h1, acc[1][s]);
            acc[2][s] = fmaf(xv, h2, acc[2][s]);
            acc[3][s] = fmaf(xv, h3, acc[3][s]);
        }
    }

    const float logit = logit_p[0];
    const float alpha = 1.0f / (1.0f + expf(-logit));
    const float beta  = 1.0f - alpha;

    #pragma unroll
    for (int j = 0; j < 4; ++j) {
        const int c = lane + 64 * j;
        const float* __restrict__ xr =
            seqs + ((size_t)(n * CC + c)) * row_stride + hw;
        float mmax = -INFINITY;
        #pragma unroll
        for (int s = 0; s < SS; ++s) {
            const float xv = xr[(size_t)s * HWW];
            const float lo = acc[j][s];
            acc[j][s] = fabsf(lo) / (fabsf(lo - xv) + 1e-6f);
            mmax = fmaxf(mmax, xv);
        }
        unsigned taken = 0u;
        float sum = 0.0f;
        #pragma unroll 1
        for (int t = 0; t < TOPK; ++t) {
            float best = -1.0f;
            int bi = 0;
            #pragma unroll
            for (int s = 0; s < SS; ++s) {
                const float v = acc[j][s];
                const bool ok = (((taken >> s) & 1u) == 0u) && (v > best);
                best = ok ? v : best;
                bi   = ok ? s : bi;
            }
            taken |= (1u << bi);
            sum += xr[(size_t)bi * HWW];
        }
        out[((size_t)(n * CC + c)) * HWW + hw] =
            alpha * (sum / 10.0f) + beta * mmax;
    }
}

// ---------------------------------------------------------------------------
extern "C" void kernel_launch(void* const* d_in, const int* in_sizes, int n_in,
                              void* d_out, int out_size, void* d_ws, size_t ws_size,
                              hipStream_t stream) {
    const float* seqs   = (const float*)d_in[0];
    const float* logitp = (const float*)d_in[1];
    float* outp = (float*)d_out;

    float* hh               = (float*)d_ws;                          // 2 KB
    unsigned short* Hsp     = (unsigned short*)((char*)d_ws + 4096); // 384 KB
    float* scorebuf         = (float*)((char*)d_ws + 524288);

    const size_t bytes_per_n = (size_t)CC * PP * sizeof(float);      // 5.4 MB
    const size_t hdr = 524288;
    const size_t avail = (ws_size > hdr) ? (ws_size - hdr) : 0;
    int chunk = (int)(avail / bytes_per_n);
    if (chunk > NN) chunk = NN;

    hipLaunchKernelGGL(build_filter_kernel, dim3(1), dim3(256), 0, stream,
                       hh, Hsp, (chunk >= 1) ? 1 : 0);

    if (chunk >= 1) {
        for (int na = 0; na < NN; na += chunk) {
            const int nc = (NN - na < chunk) ? (NN - na) : chunk;
            hipLaunchKernelGGL(conv_mfma_kernel, dim3(83, 4, nc), dim3(256), 0, stream,
                               seqs, (const unsigned short*)Hsp, scorebuf, na);
            hipLaunchKernelGGL(topk_pool_kernel, dim3(3, 64, nc), dim3(256), 0, stream,
                               seqs, (const float*)scorebuf, logitp, outp, na);
        }
    } else {
        hipLaunchKernelGGL(fallback_pool_kernel, dim3(NN * HWW), dim3(64), 0, stream,
                           seqs, logitp, hh, outp);
    }
}